// Round 14
// baseline (584.045 us; speedup 1.0000x reference)
//
#include <hip/hip_runtime.h>

#define NR 4096
#define NT 96
#define NNZ_CAP 10240
#define SREM_CAP 8192  // ALL lag-2..7 edges + lag-1 overflow live here (~5.5K expected)
#define LONG_CAP 4096
#define WLDS 8
#define SSTR 4112      // win slot stride (elements): 4096 cols + pad cell @4096
#define SHORTLAG 7     // lag <= 7 via LDS window
#define DHIST 32       // Qhist depth; safe for lag <= 31 (fallback beyond)
#define DTSTEP 3600.0f
#define LOG2_1E6 -19.931568f

__device__ __forceinline__ float RCP(float x) { return __builtin_amdgcn_rcpf(x); }
__device__ __forceinline__ float EXP2(float x) { return __builtin_amdgcn_exp2f(x); }
__device__ __forceinline__ float LOG2(float x) { return __builtin_amdgcn_logf(x); }

// Phase barrier: retire LDS ops (win visibility), bound VMEM at 12, sync.
__device__ __forceinline__ void phase_barrier() {
  asm volatile("s_waitcnt lgkmcnt(0) vmcnt(12)" ::: "memory");
  __builtin_amdgcn_s_barrier();
  asm volatile("" ::: "memory");
}

// ---------- K1: dense int mask -> CSR (old ids), SINGLE HBM pass ----------
__global__ void mc_build(const int* __restrict__ mask, int* __restrict__ rowBase,
                         int* __restrict__ rowCnt, int* __restrict__ gctr,
                         unsigned short* __restrict__ cols) {
  __shared__ unsigned short tmp[80];
  __shared__ int baseS;
  int row = blockIdx.x;
  int lane = threadIdx.x;
  const int* rs = mask + (size_t)row * NR;
  int total = 0;
  for (int j0 = 0; j0 < NR; j0 += 64) {
    int j = j0 + lane;
    int pred = (rs[j] != 0);
    unsigned long long m = __ballot(pred);
    if (pred) {
      int pos = total + __popcll(m & ((1ull << lane) - 1ull));
      if (pos < 80) tmp[pos] = (unsigned short)j;
    }
    total += __popcll(m);
  }
  if (total > 80) total = 80;
  if (lane == 0) {
    int b = atomicAdd(gctr, total);
    rowBase[row] = b;
    rowCnt[row] = total;
    baseS = b;
  }
  __syncthreads();
  int base = baseS;
  for (int e = lane; e < total; e += 64) {
    int p = base + e;
    if (p < NNZ_CAP) cols[p] = tmp[e];
  }
}

// ---------- K2: levels, (level,degree) sort, lag-split edge lists ----------
// scol4 = up to 4 LAG-1 cols (byte offs, pad=16384).
// srem row segment = [lag 2..7 entries (PRE) | lag-1 overflow (POST)].
// sremMeta: base(0..19) | nPre(20..25) | nPost(26..31).
__global__ __launch_bounds__(1024) void mc_prep(
    const int* __restrict__ rowBase, const int* __restrict__ rowCnt,
    const int* __restrict__ gctr, const unsigned short* __restrict__ colsOld,
    unsigned short* __restrict__ orderG, unsigned short* __restrict__ levNG,
    unsigned short* __restrict__ scolG, unsigned int* __restrict__ sremMeta,
    unsigned int* __restrict__ longMeta, unsigned short* __restrict__ sremG,
    unsigned short* __restrict__ longG, unsigned char* __restrict__ lsG,
    int* __restrict__ meta) {
  __shared__ unsigned short cols_s[NNZ_CAP];
  __shared__ unsigned char lev_s[NR];
  __shared__ unsigned short newid_s[NR];
  __shared__ unsigned short order_s[NR];
  __shared__ unsigned char lsrc_s[NR];
  __shared__ int cnt[1024];
  __shared__ int ws16[16];
  __shared__ int flagA[40];
  __shared__ int maxLevS;
  const int tid = threadIdx.x;
  int nnz = gctr[0];
  if (nnz > NNZ_CAP) nnz = NNZ_CAP;
  for (int e = tid; e < nnz; e += 1024) cols_s[e] = colsOld[e];
  for (int i = tid; i < 40; i += 1024) flagA[i] = 0;

  int b_r[4], e_r[4];
#pragma unroll
  for (int k = 0; k < 4; ++k) {
    int i = 4 * tid + k;
    int b = rowBase[i];
    if (b > NNZ_CAP) b = NNZ_CAP;
    int e = b + rowCnt[i];
    if (e > NNZ_CAP) e = NNZ_CAP;
    b_r[k] = b;
    e_r[k] = e;
    lev_s[i] = 0;
    lsrc_s[i] = 0;
  }
  if (tid == 0) maxLevS = 0;
  __syncthreads();

  // longest-path level relaxation, 1 barrier/pass (monotone; benign races).
  for (int pass = 0; pass < 34; ++pass) {
    int ch = 0;
#pragma unroll
    for (int k = 0; k < 4; ++k) {
      int i = 4 * tid + k;
      int lv = 0;
      for (int e = b_r[k]; e < e_r[k]; ++e) {
        int l2 = (int)lev_s[cols_s[e]] + 1;
        lv = lv > l2 ? lv : l2;
      }
      if (lv > 60) lv = 60;
      if (lv > (int)lev_s[i]) {
        lev_s[i] = (unsigned char)lv;
        ch = 1;
      }
    }
    if (ch) flagA[pass] = 1;  // benign race, all write 1
    __syncthreads();
    if (flagA[pass] == 0) break;
  }
  int lm = 0;
#pragma unroll
  for (int k = 0; k < 4; ++k) {
    int l = lev_s[4 * tid + k];
    lm = lm > l ? lm : l;
  }
  atomicMax(&maxLevS, lm);
  __syncthreads();
  const int maxLev = maxLevS;
  if (tid == 0) {
    meta[0] = maxLev + 1;
    meta[2] = (maxLev >= 32) ? 1 : 0;
  }
  if (maxLev >= 32) {  // fallback: identity order, route uses old CSR
#pragma unroll
    for (int k = 0; k < 4; ++k) {
      int i = 4 * tid + k;
      orderG[i] = (unsigned short)i;
      levNG[i] = (unsigned short)lev_s[i];
    }
    return;
  }

  // counting sort by bucket = lev*32 + min(deg,31)
  cnt[tid] = 0;
  __syncthreads();
  int bkt_r[4];
#pragma unroll
  for (int k = 0; k < 4; ++k) {
    int i = 4 * tid + k;
    int d = e_r[k] - b_r[k];
    if (d > 31) d = 31;
    int bkt = ((int)lev_s[i]) * 32 + d;
    bkt_r[k] = bkt;
    atomicAdd(&cnt[bkt], 1);
  }
  __syncthreads();
  // bucket exclusive scan via wave shuffles (2 barriers)
  {
    int v = cnt[tid];
    int lane = tid & 63, wid = tid >> 6;
    int x = v;
#pragma unroll
    for (int off = 1; off < 64; off <<= 1) {
      int y = __shfl_up(x, off);
      if (lane >= off) x += y;
    }
    if (lane == 63) ws16[wid] = x;
    __syncthreads();
    if (wid == 0) {
      int wv = (lane < 16) ? ws16[lane] : 0;
#pragma unroll
      for (int off = 1; off < 16; off <<= 1) {
        int y = __shfl_up(wv, off);
        if (lane >= off) wv += y;
      }
      if (lane < 16) ws16[lane] = wv;
    }
    __syncthreads();
    int base = wid ? ws16[wid - 1] : 0;
    cnt[tid] = base + x - v;
  }
  __syncthreads();
#pragma unroll
  for (int k = 0; k < 4; ++k) {
    int i = 4 * tid + k;
    int pos = atomicAdd(&cnt[bkt_r[k]], 1);
    order_s[pos] = (unsigned short)i;
    newid_s[i] = (unsigned short)pos;
  }
  __syncthreads();

  // emission with lag classification
#pragma unroll
  for (int k = 0; k < 4; ++k) {
    int p = 4 * tid + k;
    int oldi = order_s[p];
    orderG[p] = (unsigned short)oldi;
    int lp = (int)lev_s[oldi];
    levNG[p] = (unsigned short)lp;
    int b = rowBase[oldi];
    if (b > NNZ_CAP) b = NNZ_CAP;
    int e = b + rowCnt[oldi];
    if (e > NNZ_CAP) e = NNZ_CAP;
    int nL1 = 0, nPre = 0, nL = 0;
    for (int ee = b; ee < e; ++ee) {
      int lag = lp - (int)lev_s[cols_s[ee]];
      if (lag > SHORTLAG) ++nL;
      else if (lag == 1) ++nL1;
      else ++nPre;  // lag 2..7
    }
    int nPost = nL1 > 4 ? nL1 - 4 : 0;
    if (nPre > 63) nPre = 63;
    if (nPost > 63) nPost = 63;
    if (nL > 63) nL = 63;
    int sLen = nPre + nPost;
    int sB = sLen ? atomicAdd(&meta[4], sLen) : 0;
    int lB = nL ? atomicAdd(&meta[5], nL) : 0;
    if (sB > SREM_CAP) sB = SREM_CAP;
    if (sB + sLen > SREM_CAP) {
      sLen = SREM_CAP - sB;
      if (nPre > sLen) nPre = sLen;
      nPost = sLen - nPre;
    }
    if (lB > LONG_CAP) lB = LONG_CAP;
    if (lB + nL > LONG_CAP) nL = LONG_CAP - lB;
    unsigned short sc[4] = {16384, 16384, 16384, 16384};
    int iS = 0, cPre = 0, cPost = 0, cL = 0;
    for (int ee = b; ee < e; ++ee) {
      int cOld = cols_s[ee];
      int cN = newid_s[cOld];
      int lag = lp - (int)lev_s[cOld];
      if (lag > SHORTLAG) {
        if (cL < nL) { longG[lB + cL] = (unsigned short)(cN << 2); ++cL; }
        lsrc_s[cN] = 1;  // benign race, all write 1
      } else if (lag == 1) {
        if (iS < 4) sc[iS++] = (unsigned short)(cN << 2);
        else if (cPost < nPost) {
          sremG[sB + nPre + cPost] = (unsigned short)(cN << 2);
          ++cPost;
        }
      } else {  // lag 2..7 -> PRE segment
        if (cPre < nPre) {
          sremG[sB + cPre] = (unsigned short)(cN << 2);
          ++cPre;
        }
      }
    }
    scolG[4 * p + 0] = sc[0];
    scolG[4 * p + 1] = sc[1];
    scolG[4 * p + 2] = sc[2];
    scolG[4 * p + 3] = sc[3];
    sremMeta[p] = (unsigned)sB | ((unsigned)nPre << 20) | ((unsigned)nPost << 26);
    longMeta[p] = (unsigned)lB | ((unsigned)nL << 20);
  }
  if (tid == 0) meta[1] = newid_s[NR - 1];
  __syncthreads();
#pragma unroll
  for (int k = 0; k < 4; ++k) {
    int p = 4 * tid + k;
    lsG[p] = lsrc_s[p];
  }
}

// ---------- K3: permute lateral inflows into sorted order ----------
__global__ void mc_permlat(const float* __restrict__ lat,
                           const unsigned short* __restrict__ orderG,
                           float* __restrict__ latP) {
  int g = blockIdx.x * 256 + threadIdx.x;  // NT*NR threads
  int t = g >> 12, p = g & 4095;
  latP[g] = lat[t * NR + orderG[p]];
}

// ---------- K4: diagonal route, lag-split PRE/POST bodies ----------
// POST(t): after barrier — only lag-1 window reads + combine + writes.
// PRE(t+1): before barrier — lat prefetch, lag>=2 window reads, Qhist
// long-lag reads, and the coefficient chain (needs only q1 = Q[t]).
// Race-free: a PRE read of cell (slot tn&7, col c) collides with a
// same-phase write only if lag == 1 (mod 8) — excluded from PRE set.
__global__ __launch_bounds__(1024, 4) void mc_route(
    const float* __restrict__ lat, const float* __restrict__ latP,
    const float* __restrict__ initQ, const float* __restrict__ Lg,
    const float* __restrict__ Sg, const float* __restrict__ mng,
    const float* __restrict__ wcg, const float* __restrict__ weg,
    const float* __restrict__ dcg, const float* __restrict__ deg,
    const int* __restrict__ rowBase, const int* __restrict__ rowCnt,
    const unsigned short* __restrict__ colsOld,
    const unsigned short* __restrict__ orderG,
    const unsigned short* __restrict__ levNG,
    const unsigned short* __restrict__ scolG,
    const unsigned int* __restrict__ sremMeta,
    const unsigned int* __restrict__ longMeta,
    const unsigned short* __restrict__ sremG,
    const unsigned short* __restrict__ longG,
    const unsigned char* __restrict__ lsG, const int* __restrict__ meta,
    float* Qhist, float* __restrict__ out, int usePerm) {
  __shared__ float win_s[WLDS * SSTR];        // 131584 B
  __shared__ unsigned short srem_s[SREM_CAP]; // 16384 B
  __shared__ unsigned short long_s[LONG_CAP]; // 8192 B
  const int tid = threadIdx.x;
  const int nlv = meta[0];
  const int fb = meta[2];
  const int outletNew = meta[1];
  const float* latB = usePerm ? latP : lat;

  if (!fb) {
    int sc_r[4][4];
    int lev_r[4], io_r[4], ls_r[4], wOff_r[4];
    unsigned int smeta_r[4], lmeta_r[4];
    const float* latcol_r[4];
    float lwc_r[4], we_r[4], ldc_r[4], de_r[4], lvk_r[4], lgSL_r[4], L_r[4];
    float ip_r[4], q1_r[4], q2_r[4], latN_r[4];
    float psum_r[4], C0_r[4], C1_r[4], C2_r[4], inv_r[4];

    int nSrem = meta[4];
    if (nSrem > SREM_CAP) nSrem = SREM_CAP;
    int nLong = meta[5];
    if (nLong > LONG_CAP) nLong = LONG_CAP;
    for (int e = tid; e < nSrem; e += 1024) srem_s[e] = sremG[e];
    for (int e = tid; e < nLong; e += 1024) long_s[e] = longG[e];
    if (tid < WLDS) win_s[tid * SSTR + 4096] = 0.f;  // pad cells (byte 16384)

#pragma unroll
    for (int k = 0; k < 4; ++k) {
      int p = tid + k * 1024;
      int oldi = orderG[p];
      lev_r[k] = (int)levNG[p];
      uint2 cc = *(const uint2*)(scolG + 4 * p);
      sc_r[k][0] = cc.x & 0xFFFFu;  // byte offsets within a win slot
      sc_r[k][1] = cc.x >> 16;
      sc_r[k][2] = cc.y & 0xFFFFu;
      sc_r[k][3] = cc.y >> 16;
      smeta_r[k] = sremMeta[p];
      lmeta_r[k] = longMeta[p];
      ls_r[k] = (int)lsG[p];
      io_r[k] = (p == outletNew);
      float Lv = Lg[oldi];
      float sS = fmaxf(Sg[oldi], 1e-6f);
      float mnv = fmaxf(mng[oldi], 1e-3f);
      lvk_r[k] = 0.7369656f + 0.5f * LOG2(sS) - LOG2(mnv);  // log2(5/3*sqrt(S)/n)
      lgSL_r[k] = LOG2(sS * Lv);
      L_r[k] = Lv;
      lwc_r[k] = LOG2(wcg[oldi]);
      we_r[k] = weg[oldi];
      ldc_r[k] = LOG2(dcg[oldi]);
      de_r[k] = deg[oldi];
      float q0 = initQ[oldi];
      q1_r[k] = q0;
      q2_r[k] = q0;
      ip_r[k] = 0.f;
      psum_r[k] = 0.f;
      wOff_r[k] = 0;  // byte offset of current win slot
      latcol_r[k] = latB + (usePerm ? p : oldi);
      latN_r[k] = *latcol_r[k];  // t=0 prefetch
      // initial coefficients for t=0 (used by lev-0 rows' first POST)
      float Qref = fmaxf(q0, 0.1f);
      float lq = LOG2(Qref);
      float lgW = fmaf(we_r[k], lq, lwc_r[k]);
      float W = EXP2(lgW);
      float aD = fmaf(de_r[k], lq, ldc_r[k]);
      float Dd = EXP2(aD);
      float lgR = fmaxf(lgW + aD - LOG2(fmaf(2.f, Dd, W)), LOG2_1E6);
      float lgc = fmaf(0.66666667f, lgR, lvk_r[k]);
      float K = fmaxf(Lv * EXP2(-lgc), 360.f);
      float ratio = EXP2(lq - lgW - lgc - lgSL_r[k]);
      float X = fmaxf(fmaf(-0.5f, ratio, 0.5f), 0.f);
      float twoK = K + K;
      float twoKX = twoK * X;
      C0_r[k] = fmaxf(DTSTEP - twoKX, 0.f);
      C1_r[k] = DTSTEP + twoKX;
      C2_r[k] = fmaxf(twoK - twoKX - DTSTEP, 0.f);
      inv_r[k] = RCP(C0_r[k] + C1_r[k] + C2_r[k]);
    }
    __syncthreads();

// POST: the barrier-dependent half. Reads only lag-1 cells of slot tt&7.
#define POST(k, tt)                                                             \
  {                                                                             \
    const int p = tid + (k)*1024;                                               \
    const char* wb = (const char*)win_s + wOff_r[k];                            \
    float v0 = *(const float*)(wb + sc_r[k][0]);                                \
    float v1 = *(const float*)(wb + sc_r[k][1]);                                \
    float v2 = *(const float*)(wb + sc_r[k][2]);                                \
    float v3 = *(const float*)(wb + sc_r[k][3]);                                \
    float ext = 0.f;                                                            \
    const int nPost = (int)(smeta_r[k] >> 26);                                  \
    if (nPost) {                                                                \
      const int sBp = (int)(smeta_r[k] & 0xFFFFFu) +                            \
                      (int)((smeta_r[k] >> 20) & 63);                           \
      for (int e = 0; e < nPost; ++e)                                           \
        ext += *(const float*)(wb + srem_s[sBp + e]);                           \
    }                                                                           \
    float sup = psum_r[k] + ((v0 + v1) + (v2 + v3)) + ext;                      \
    float Icurr = sup + latN_r[k];                                              \
    float Qout = fmaxf(                                                         \
        (C0_r[k] * Icurr + C1_r[k] * ip_r[k] + C2_r[k] * q2_r[k]) * inv_r[k],   \
        0.f);                                                                   \
    *(float*)((char*)win_s + wOff_r[k] + (p << 2)) = Qout;                      \
    if (ls_r[k]) Qhist[(((tt) & 31) << 12) | p] = Qout;                         \
    if (io_r[k]) out[tt] = Qout;                                                \
    ip_r[k] = Icurr;                                                            \
    q2_r[k] = q1_r[k];                                                          \
    q1_r[k] = Qout;                                                             \
    wOff_r[k] =                                                                 \
        (wOff_r[k] == (WLDS - 1) * SSTR * 4) ? 0 : wOff_r[k] + SSTR * 4;        \
  }

// PRE: barrier-independent half for time tn (= next). Uses already-visible
// data: lag>=2 win cells (slot tn&7 == current wOff after advance), Qhist
// long-lag reads, lat; coefficient chain from q1 (= Q[tn-1]).
#define PRE(k, tn)                                                              \
  {                                                                             \
    latN_r[k] = latcol_r[k][(tn) << 12];                                        \
    const char* wbn = (const char*)win_s + wOff_r[k];                           \
    float ps = 0.f;                                                             \
    const int nPre = (int)((smeta_r[k] >> 20) & 63);                            \
    if (nPre) {                                                                 \
      const int sB = (int)(smeta_r[k] & 0xFFFFFu);                              \
      for (int e = 0; e < nPre; ++e)                                            \
        ps += *(const float*)(wbn + srem_s[sB + e]);                            \
    }                                                                           \
    const int lC = (int)(lmeta_r[k] >> 20);                                     \
    if (lC) {                                                                   \
      const int lB = (int)(lmeta_r[k] & 0xFFFFFu);                              \
      const char* qb = (const char*)Qhist + (((tn) & 31) << 14);                \
      for (int e = 0; e < lC; ++e) ps += *(const float*)(qb + long_s[lB + e]);  \
    }                                                                           \
    psum_r[k] = ps;                                                             \
    float Qref = fmaxf(q1_r[k], 0.1f);                                          \
    float lq = LOG2(Qref);                                                      \
    float lgW = fmaf(we_r[k], lq, lwc_r[k]);                                    \
    float W = EXP2(lgW);                                                        \
    float aD = fmaf(de_r[k], lq, ldc_r[k]);                                     \
    float Dd = EXP2(aD);                                                        \
    float lgR = fmaxf(lgW + aD - LOG2(fmaf(2.f, Dd, W)), LOG2_1E6);             \
    float lgc = fmaf(0.66666667f, lgR, lvk_r[k]);                               \
    float K = fmaxf(L_r[k] * EXP2(-lgc), 360.f);                                \
    float ratio = EXP2(lq - lgW - lgc - lgSL_r[k]);                             \
    float X = fmaxf(fmaf(-0.5f, ratio, 0.5f), 0.f);                             \
    float twoK = K + K;                                                         \
    float twoKX = twoK * X;                                                     \
    C0_r[k] = fmaxf(DTSTEP - twoKX, 0.f);                                       \
    C1_r[k] = DTSTEP + twoKX;                                                   \
    C2_r[k] = fmaxf(twoK - twoKX - DTSTEP, 0.f);                                \
    inv_r[k] = RCP(C0_r[k] + C1_r[k] + C2_r[k]);                                \
  }

    const int nDiag = NT + nlv - 1;
    for (int s = 0; s < nDiag; ++s) {
      // POST first (critical path), then PRE (fills barrier slack)
#pragma unroll
      for (int k = 0; k < 4; ++k) {
        int t = s - lev_r[k];
        if ((unsigned)t < (unsigned)NT) POST(k, t);
      }
#pragma unroll
      for (int k = 0; k < 4; ++k) {
        int tn = s + 1 - lev_r[k];
        if ((unsigned)tn < (unsigned)NT) PRE(k, tn);
      }
      phase_barrier();
    }
  } else {
    // safety fallback (maxLev >= 32, statistically impossible): per-t sweep
    unsigned short* colsF = (unsigned short*)win_s;  // reuse LDS
    int b_r[4], e_r[4], lev_r[4];
    float lwc_r[4], we_r[4], ldc_r[4], de_r[4], lvk_r[4], SL_r[4], L_r[4];
    float ip_r[4], q1_r[4], q2_r[4];
    for (int e = tid; e < NNZ_CAP; e += 1024) colsF[e] = colsOld[e];
#pragma unroll
    for (int k = 0; k < 4; ++k) {
      int i = tid + k * 1024;
      lev_r[k] = (int)levNG[i];
      int b = rowBase[i];
      if (b > NNZ_CAP) b = NNZ_CAP;
      int e = b + rowCnt[i];
      if (e > NNZ_CAP) e = NNZ_CAP;
      b_r[k] = b;
      e_r[k] = e;
      float Lv = Lg[i];
      float sS = fmaxf(Sg[i], 1e-6f);
      float mnv = fmaxf(mng[i], 1e-3f);
      lvk_r[k] = 0.7369656f + 0.5f * LOG2(sS) - LOG2(mnv);
      SL_r[k] = sS * Lv;
      L_r[k] = Lv;
      lwc_r[k] = LOG2(wcg[i]);
      we_r[k] = weg[i];
      ldc_r[k] = LOG2(dcg[i]);
      de_r[k] = deg[i];
      float q0 = initQ[i];
      q1_r[k] = q0;
      q2_r[k] = q0;
      ip_r[k] = 0.f;
    }
    __syncthreads();
    for (int t = 0; t < NT; ++t) {
      for (int l = 0; l < nlv; ++l) {
#pragma unroll
        for (int k = 0; k < 4; ++k) {
          if (lev_r[k] == l) {
            int i = tid + k * 1024;
            float latv = lat[t * NR + i];
            float Qref = fmaxf(q1_r[k], 0.1f);
            float lq = LOG2(Qref);
            float lgW = fmaf(we_r[k], lq, lwc_r[k]);
            float W = EXP2(lgW);
            float aD = fmaf(de_r[k], lq, ldc_r[k]);
            float Dd = EXP2(aD);
            float lgR = fmaxf(lgW + aD - LOG2(fmaf(2.f, Dd, W)), LOG2_1E6);
            float c = fmaxf(EXP2(fmaf(0.66666667f, lgR, lvk_r[k])), 0.01f);
            float K = fmaxf(L_r[k] * RCP(c), 360.f);
            float X =
                fmaxf(0.5f - 0.5f * Qref * RCP(fmaf(W * c, SL_r[k], 1e-6f)), 0.f);
            float twoKX = 2.f * K * X;
            float C0 = fmaxf(DTSTEP - twoKX, 0.f);
            float C1 = DTSTEP + twoKX;
            float C2 = fmaxf(2.f * K - twoKX - DTSTEP, 0.f);
            float inv = RCP(C0 + C1 + C2);
            float sup = 0.f;
            for (int e = b_r[k]; e < e_r[k]; ++e) sup += Qhist[colsF[e]];
            float Icurr = sup + latv;
            float Qout =
                fmaxf((C0 * Icurr + C1 * ip_r[k] + C2 * q2_r[k]) * inv, 0.f);
            Qhist[i] = Qout;
            ip_r[k] = Icurr;
            q2_r[k] = q1_r[k];
            q1_r[k] = Qout;
            if (i == NR - 1) out[t] = Qout;
          }
        }
        __syncthreads();
      }
    }
  }
}

extern "C" void kernel_launch(void* const* d_in, const int* in_sizes, int n_in,
                              void* d_out, int out_size, void* d_ws, size_t ws_size,
                              hipStream_t stream) {
  const float* lat = (const float*)d_in[0];
  const float* iQ = (const float*)d_in[1];
  const float* Lg = (const float*)d_in[2];
  const float* Sg = (const float*)d_in[3];
  const float* mng = (const float*)d_in[4];
  const float* wcg = (const float*)d_in[5];
  const float* weg = (const float*)d_in[6];
  const float* dcg = (const float*)d_in[7];
  const float* deg = (const float*)d_in[8];
  const int* mask = (const int*)d_in[9];
  float* out = (float*)d_out;

  char* w = (char*)d_ws;
  int* rowBase = (int*)w;                        w += NR * 4;
  int* rowCnt = (int*)w;                         w += NR * 4;
  int* gctr = (int*)w;                           w += 16;
  int* meta = (int*)w;                           w += 32;  // [0]nlv [1]outlet [2]fb [4]sremCur [5]longCur
  unsigned short* colsOld = (unsigned short*)w;  w += NNZ_CAP * 2;
  unsigned short* orderG = (unsigned short*)w;   w += NR * 2;
  unsigned short* levNG = (unsigned short*)w;    w += NR * 2;
  unsigned short* scolG = (unsigned short*)w;    w += NR * 4 * 2;
  unsigned int* sremMeta = (unsigned int*)w;     w += NR * 4;
  unsigned int* longMeta = (unsigned int*)w;     w += NR * 4;
  unsigned short* sremG = (unsigned short*)w;    w += SREM_CAP * 2;
  unsigned short* longG = (unsigned short*)w;    w += LONG_CAP * 2;
  unsigned char* lsG = (unsigned char*)w;        w += NR;
  w += 16 - ((size_t)w & 15);
  float* Qhist = (float*)w;                      w += (size_t)DHIST * NR * 4;
  float* latP = (float*)w;                       w += (size_t)NT * NR * 4;
  size_t need = (size_t)(w - (char*)d_ws);
  int usePerm = (ws_size >= need) ? 1 : 0;

  hipMemsetAsync(gctr, 0, 48, stream);  // gctr + meta (incl. cursors)
  mc_build<<<NR, 64, 0, stream>>>(mask, rowBase, rowCnt, gctr, colsOld);
  mc_prep<<<1, 1024, 0, stream>>>(rowBase, rowCnt, gctr, colsOld, orderG, levNG,
                                  scolG, sremMeta, longMeta, sremG, longG, lsG,
                                  meta);
  if (usePerm)
    mc_permlat<<<(NT * NR) / 256, 256, 0, stream>>>(lat, orderG, latP);
  mc_route<<<1, 1024, 0, stream>>>(lat, latP, iQ, Lg, Sg, mng, wcg, weg, dcg,
                                   deg, rowBase, rowCnt, colsOld, orderG, levNG,
                                   scolG, sremMeta, longMeta, sremG, longG, lsG,
                                   meta, Qhist, out, usePerm);
}

// Round 15
// 464.435 us; speedup vs baseline: 1.2575x; 1.2575x over previous
//
#include <hip/hip_runtime.h>

#define NR 4096
#define NT 96
#define NNZ_CAP 10240
#define SREM_CAP 4096
#define LONG_CAP 4096
#define WLDS 8
#define SSTR 4112          // win slot stride (elements): 4096 cols + pad cell @4096
#define DHIST 32
#define DTSTEP 3600.0f
#define LOG2_1E6 -19.931568f

__device__ __forceinline__ float RCP(float x) { return __builtin_amdgcn_rcpf(x); }
__device__ __forceinline__ float EXP2(float x) { return __builtin_amdgcn_exp2f(x); }
__device__ __forceinline__ float LOG2(float x) { return __builtin_amdgcn_logf(x); }

// Raw phase barrier: retire LDS ops, bound (not drain) VMEM, sync.
// lat prefetch + Qhist stores stay in flight across the barrier; Qhist
// store->read slack is >= 8 phases, vmcnt(6) forces retirement within ~2.
__device__ __forceinline__ void phase_barrier() {
  asm volatile("s_waitcnt lgkmcnt(0) vmcnt(6)" ::: "memory");
  __builtin_amdgcn_s_barrier();
  asm volatile("" ::: "memory");
}

// ---------- K1: dense int mask -> CSR (old ids), SINGLE HBM pass ----------
__global__ void mc_build(const int* __restrict__ mask, int* __restrict__ rowBase,
                         int* __restrict__ rowCnt, int* __restrict__ gctr,
                         unsigned short* __restrict__ cols) {
  __shared__ unsigned short tmp[80];
  __shared__ int baseS;
  int row = blockIdx.x;
  int lane = threadIdx.x;
  const int* rs = mask + (size_t)row * NR;
  int total = 0;
  for (int j0 = 0; j0 < NR; j0 += 64) {
    int j = j0 + lane;
    int pred = (rs[j] != 0);
    unsigned long long m = __ballot(pred);
    if (pred) {
      int pos = total + __popcll(m & ((1ull << lane) - 1ull));
      if (pos < 80) tmp[pos] = (unsigned short)j;
    }
    total += __popcll(m);
  }
  if (total > 80) total = 80;
  if (lane == 0) {
    int b = atomicAdd(gctr, total);
    rowBase[row] = b;
    rowCnt[row] = total;
    baseS = b;
  }
  __syncthreads();
  int base = baseS;
  for (int e = lane; e < total; e += 64) {
    int p = base + e;
    if (p < NNZ_CAP) cols[p] = tmp[e];
  }
}

// ---------- K2: levels, (level,degree) sort, scol4(reg) + LDS side lists ----
__global__ __launch_bounds__(1024) void mc_prep(
    const int* __restrict__ rowBase, const int* __restrict__ rowCnt,
    const int* __restrict__ gctr, const unsigned short* __restrict__ colsOld,
    unsigned short* __restrict__ orderG, unsigned short* __restrict__ levNG,
    unsigned short* __restrict__ scolG, unsigned int* __restrict__ sremMeta,
    unsigned int* __restrict__ longMeta, unsigned short* __restrict__ sremG,
    unsigned short* __restrict__ longG, unsigned char* __restrict__ lsG,
    int* __restrict__ meta) {
  __shared__ unsigned short cols_s[NNZ_CAP];
  __shared__ unsigned char lev_s[NR];
  __shared__ unsigned short newid_s[NR];
  __shared__ unsigned short order_s[NR];
  __shared__ unsigned char lsrc_s[NR];
  __shared__ int cnt[1024];
  __shared__ int sbuf[1024];
  __shared__ int maxLevS, flagS;
  const int tid = threadIdx.x;
  int nnz = gctr[0];
  if (nnz > NNZ_CAP) nnz = NNZ_CAP;
  for (int e = tid; e < nnz; e += 1024) cols_s[e] = colsOld[e];

  int b_r[4], e_r[4];
#pragma unroll
  for (int k = 0; k < 4; ++k) {
    int i = 4 * tid + k;
    int b = rowBase[i];
    if (b > NNZ_CAP) b = NNZ_CAP;
    int e = b + rowCnt[i];
    if (e > NNZ_CAP) e = NNZ_CAP;
    b_r[k] = b;
    e_r[k] = e;
    lev_s[i] = 0;
    lsrc_s[i] = 0;
  }
  if (tid == 0) maxLevS = 0;
  __syncthreads();

  // longest-path level relaxation (acyclic: cols strictly < row)
  for (int pass = 0; pass < 48; ++pass) {
    if (tid == 0) flagS = 0;
    __syncthreads();
    int ch = 0;
#pragma unroll
    for (int k = 0; k < 4; ++k) {
      int i = 4 * tid + k;
      int lv = 0;
      for (int e = b_r[k]; e < e_r[k]; ++e) {
        int l2 = (int)lev_s[cols_s[e]] + 1;
        lv = lv > l2 ? lv : l2;
      }
      if (lv > 127) lv = 127;
      if (lv > (int)lev_s[i]) {
        lev_s[i] = (unsigned char)lv;
        ch = 1;
      }
    }
    if (ch) flagS = 1;
    __syncthreads();
    int done = (flagS == 0);
    __syncthreads();
    if (done) break;
  }
  int lm = 0;
#pragma unroll
  for (int k = 0; k < 4; ++k) {
    int l = lev_s[4 * tid + k];
    lm = lm > l ? lm : l;
  }
  atomicMax(&maxLevS, lm);
  __syncthreads();
  const int maxLev = maxLevS;
  if (tid == 0) {
    meta[0] = maxLev + 1;
    meta[2] = (maxLev >= DHIST) ? 1 : 0;
  }
  if (maxLev >= DHIST) {  // fallback: identity order, route uses old CSR
#pragma unroll
    for (int k = 0; k < 4; ++k) {
      int i = 4 * tid + k;
      orderG[i] = (unsigned short)i;
      levNG[i] = (unsigned short)lev_s[i];
    }
    return;
  }

  // counting sort by bucket = lev*32 + min(deg,31)
  cnt[tid] = 0;
  __syncthreads();
  int bkt_r[4];
#pragma unroll
  for (int k = 0; k < 4; ++k) {
    int i = 4 * tid + k;
    int d = e_r[k] - b_r[k];
    if (d > 31) d = 31;
    int bkt = ((int)lev_s[i]) * 32 + d;
    bkt_r[k] = bkt;
    atomicAdd(&cnt[bkt], 1);
  }
  __syncthreads();
  int v = cnt[tid];
  sbuf[tid] = v;
  __syncthreads();
  for (int off = 1; off < 1024; off <<= 1) {
    int add = tid >= off ? sbuf[tid - off] : 0;
    __syncthreads();
    sbuf[tid] += add;
    __syncthreads();
  }
  cnt[tid] = sbuf[tid] - v;  // exclusive start -> cursor
  __syncthreads();
#pragma unroll
  for (int k = 0; k < 4; ++k) {
    int i = 4 * tid + k;
    int pos = atomicAdd(&cnt[bkt_r[k]], 1);
    order_s[pos] = (unsigned short)i;
    newid_s[i] = (unsigned short)pos;
  }
  __syncthreads();

  // emission: per new-row p -> scol4 (<=4 short cols, pad=4096), srem, long
#pragma unroll
  for (int k = 0; k < 4; ++k) {
    int p = 4 * tid + k;
    int oldi = order_s[p];
    orderG[p] = (unsigned short)oldi;
    int lp = (int)lev_s[oldi];
    levNG[p] = (unsigned short)lp;
    int b = rowBase[oldi];
    if (b > NNZ_CAP) b = NNZ_CAP;
    int e = b + rowCnt[oldi];
    if (e > NNZ_CAP) e = NNZ_CAP;
    int nS = 0, nR = 0, nL = 0;
    for (int ee = b; ee < e; ++ee) {
      int lag = lp - (int)lev_s[cols_s[ee]];
      if (lag < WLDS) {
        if (nS < 4) ++nS; else ++nR;
      } else ++nL;
    }
    if (nR > 63) nR = 63;
    if (nL > 63) nL = 63;
    int sB = nR ? atomicAdd(&meta[4], nR) : 0;
    int lB = nL ? atomicAdd(&meta[5], nL) : 0;
    if (sB > SREM_CAP) sB = SREM_CAP;
    if (sB + nR > SREM_CAP) nR = SREM_CAP - sB;
    if (lB > LONG_CAP) lB = LONG_CAP;
    if (lB + nL > LONG_CAP) nL = LONG_CAP - lB;
    unsigned short sc[4] = {4096, 4096, 4096, 4096};
    int iS = 0, cR = 0, cL = 0;
    for (int ee = b; ee < e; ++ee) {
      int cOld = cols_s[ee];
      int cN = newid_s[cOld];
      int lag = lp - (int)lev_s[cOld];
      if (lag < WLDS) {
        if (iS < 4) sc[iS++] = (unsigned short)cN;
        else if (cR < nR) { sremG[sB + cR] = (unsigned short)cN; ++cR; }
      } else {
        if (cL < nL) { longG[lB + cL] = (unsigned short)cN; ++cL; }
        lsrc_s[cN] = 1;  // benign race, all write 1
      }
    }
    scolG[4 * p + 0] = sc[0];
    scolG[4 * p + 1] = sc[1];
    scolG[4 * p + 2] = sc[2];
    scolG[4 * p + 3] = sc[3];
    sremMeta[p] = (unsigned)sB | ((unsigned)nR << 20) | ((unsigned)iS << 26);
    longMeta[p] = (unsigned)lB | ((unsigned)nL << 20);
  }
  if (tid == 0) meta[1] = newid_s[NR - 1];
  __syncthreads();
#pragma unroll
  for (int k = 0; k < 4; ++k) {
    int p = 4 * tid + k;
    lsG[p] = lsrc_s[p];
  }
}

// ---------- K3: permute lateral inflows into sorted order ----------
__global__ void mc_permlat(const float* __restrict__ lat,
                           const unsigned short* __restrict__ orderG,
                           float* __restrict__ latP) {
  int g = blockIdx.x * 256 + threadIdx.x;  // NT*NR threads
  int t = g >> 12, p = g & 4095;
  latP[g] = lat[t * NR + orderG[p]];
}

// ---------- K4: diagonal-pipelined route, mem-first body, raw barriers -----
__global__ __launch_bounds__(1024, 4) void mc_route(
    const float* __restrict__ lat, const float* __restrict__ latP,
    const float* __restrict__ initQ, const float* __restrict__ Lg,
    const float* __restrict__ Sg, const float* __restrict__ mng,
    const float* __restrict__ wcg, const float* __restrict__ weg,
    const float* __restrict__ dcg, const float* __restrict__ deg,
    const int* __restrict__ rowBase, const int* __restrict__ rowCnt,
    const unsigned short* __restrict__ colsOld,
    const unsigned short* __restrict__ orderG,
    const unsigned short* __restrict__ levNG,
    const unsigned short* __restrict__ scolG,
    const unsigned int* __restrict__ sremMeta,
    const unsigned int* __restrict__ longMeta,
    const unsigned short* __restrict__ sremG,
    const unsigned short* __restrict__ longG,
    const unsigned char* __restrict__ lsG, const int* __restrict__ meta,
    float* Qhist, float* __restrict__ out, int usePerm) {
  __shared__ float win_s[WLDS * SSTR];        // 131584 B
  __shared__ unsigned short srem_s[SREM_CAP]; // 8192 B
  __shared__ unsigned short long_s[LONG_CAP]; // 8192 B
  const int tid = threadIdx.x;
  const int nlv = meta[0];
  const int fb = meta[2];
  const int outletNew = meta[1];
  const float* latB = usePerm ? latP : lat;

  if (!fb) {
    int sc_r[4][4];
    int lev_r[4], io_r[4], ls_r[4], wOff_r[4], nsc_r[4];
    unsigned int smeta_r[4], lmeta_r[4];
    const float* latp_r[4];
    float lwc_r[4], we_r[4], ldc_r[4], de_r[4], lvk_r[4], lgSL_r[4], L_r[4];
    float ip_r[4], q1_r[4], q2_r[4], latN_r[4];

    int nSrem = meta[4];
    if (nSrem > SREM_CAP) nSrem = SREM_CAP;
    int nLong = meta[5];
    if (nLong > LONG_CAP) nLong = LONG_CAP;
    for (int e = tid; e < nSrem; e += 1024) srem_s[e] = sremG[e];
    for (int e = tid; e < nLong; e += 1024) long_s[e] = longG[e];
    if (tid < WLDS) win_s[tid * SSTR + 4096] = 0.f;  // pad cells

#pragma unroll
    for (int k = 0; k < 4; ++k) {
      int p = tid + k * 1024;
      int oldi = orderG[p];
      lev_r[k] = (int)levNG[p];
      uint2 cc = *(const uint2*)(scolG + 4 * p);
      sc_r[k][0] = cc.x & 0xFFFFu;
      sc_r[k][1] = cc.x >> 16;
      sc_r[k][2] = cc.y & 0xFFFFu;
      sc_r[k][3] = cc.y >> 16;
      smeta_r[k] = sremMeta[p];
      nsc_r[k] = (int)(smeta_r[k] >> 26);
      lmeta_r[k] = longMeta[p];
      ls_r[k] = (int)lsG[p];
      io_r[k] = (p == outletNew);
      float Lv = Lg[oldi];
      float sS = fmaxf(Sg[oldi], 1e-6f);
      float mnv = fmaxf(mng[oldi], 1e-3f);
      lvk_r[k] = 0.7369656f + 0.5f * LOG2(sS) - LOG2(mnv);  // log2(5/3*sqrt(S)/n)
      lgSL_r[k] = LOG2(sS * Lv);
      L_r[k] = Lv;
      lwc_r[k] = LOG2(wcg[oldi]);
      we_r[k] = weg[oldi];
      ldc_r[k] = LOG2(dcg[oldi]);
      de_r[k] = deg[oldi];
      float q0 = initQ[oldi];
      q1_r[k] = q0;
      q2_r[k] = q0;
      ip_r[k] = 0.f;
      wOff_r[k] = 0;
      latp_r[k] = latB + (usePerm ? p : oldi);
      latN_r[k] = *latp_r[k];  // t=0 prefetch
    }
    __syncthreads();

#define BODY(k, tt)                                                             \
  {                                                                             \
    const int p = tid + (k)*1024;                                               \
    const float latv = latN_r[k];                                               \
    latp_r[k] += ((tt) + 1 < NT) ? NR : 0;                                      \
    latN_r[k] = *latp_r[k]; /* issued early, consumed next phase */             \
    const int wB = wOff_r[k];                                                   \
    float v0 = win_s[wB + sc_r[k][0]];                                          \
    float v1 = win_s[wB + sc_r[k][1]];                                          \
    float v23 = 0.f;                                                            \
    if (nsc_r[k] > 2)                                                           \
      v23 = win_s[wB + sc_r[k][2]] + win_s[wB + sc_r[k][3]];                    \
    float ssum = 0.f;                                                           \
    const int sC = (int)((smeta_r[k] >> 20) & 63);                              \
    if (sC) {                                                                   \
      const int sB = (int)(smeta_r[k] & 0xFFFFFu);                              \
      for (int e = 0; e < sC; ++e) ssum += win_s[wB + srem_s[sB + e]];          \
    }                                                                           \
    float lsum = 0.f;                                                           \
    const int lC = (int)(lmeta_r[k] >> 20);                                     \
    if (lC) {                                                                   \
      const int lB = (int)(lmeta_r[k] & 0xFFFFFu);                              \
      const float* qb = Qhist + (((tt)&31) << 12);                              \
      for (int e = 0; e < lC; ++e) lsum += qb[long_s[lB + e]];                  \
    }                                                                           \
    float Qref = fmaxf(q1_r[k], 0.1f);                                          \
    float lq = LOG2(Qref);                                                      \
    float lgW = fmaf(we_r[k], lq, lwc_r[k]);                                    \
    float W = EXP2(lgW);                                                        \
    float aD = fmaf(de_r[k], lq, ldc_r[k]);                                     \
    float Dd = EXP2(aD);                                                        \
    float lgR = fmaxf(lgW + aD - LOG2(fmaf(2.f, Dd, W)), LOG2_1E6);             \
    float lgc = fmaf(0.66666667f, lgR, lvk_r[k]);                               \
    float K = fmaxf(L_r[k] * EXP2(-lgc), 360.f);                                \
    float ratio = EXP2(lq - lgW - lgc - lgSL_r[k]);                             \
    float X = fmaxf(fmaf(-0.5f, ratio, 0.5f), 0.f);                             \
    float twoK = K + K;                                                         \
    float twoKX = twoK * X;                                                     \
    float C0 = fmaxf(DTSTEP - twoKX, 0.f);                                      \
    float C1 = DTSTEP + twoKX;                                                  \
    float C2 = fmaxf(twoK - twoKX - DTSTEP, 0.f);                               \
    float inv = RCP(C0 + C1 + C2);                                              \
    float sup = ((v0 + v1) + v23) + (ssum + lsum);                              \
    float Icurr = sup + latv;                                                   \
    float Qout = fmaxf((C0 * Icurr + C1 * ip_r[k] + C2 * q2_r[k]) * inv, 0.f);  \
    win_s[wB + p] = Qout;                                                       \
    if (ls_r[k]) Qhist[(((tt)&31) << 12) | p] = Qout;                           \
    if (io_r[k]) out[tt] = Qout;                                                \
    ip_r[k] = Icurr;                                                            \
    q2_r[k] = q1_r[k];                                                          \
    q1_r[k] = Qout;                                                             \
    wOff_r[k] = (wOff_r[k] == (WLDS - 1) * SSTR) ? 0 : wOff_r[k] + SSTR;        \
  }

#define BODYC(k, s)                                                            \
  {                                                                            \
    int t = (s)-lev_r[k];                                                      \
    if ((unsigned)t < (unsigned)NT) BODY(k, t)                                 \
  }

    // ramp-up
    for (int s = 0; s < nlv - 1; ++s) {
#pragma unroll
      for (int k = 0; k < 4; ++k) BODYC(k, s);
      phase_barrier();
    }
    // steady: all rows active
    for (int s = nlv - 1; s < NT; ++s) {
#pragma unroll
      for (int k = 0; k < 4; ++k) {
        int t = s - lev_r[k];
        BODY(k, t);
      }
      phase_barrier();
    }
    // drain
    for (int s = NT; s < NT + nlv - 1; ++s) {
#pragma unroll
      for (int k = 0; k < 4; ++k) BODYC(k, s);
      phase_barrier();
    }
  } else {
    // safety fallback (nlv > DHIST, statistically impossible): per-t level sweep
    unsigned short* colsF = (unsigned short*)win_s;  // reuse LDS
    int b_r[4], e_r[4], lev_r[4];
    float lwc_r[4], we_r[4], ldc_r[4], de_r[4], lvk_r[4], SL_r[4], L_r[4];
    float ip_r[4], q1_r[4], q2_r[4];
    for (int e = tid; e < NNZ_CAP; e += 1024) colsF[e] = colsOld[e];
#pragma unroll
    for (int k = 0; k < 4; ++k) {
      int i = tid + k * 1024;
      lev_r[k] = (int)levNG[i];
      int b = rowBase[i];
      if (b > NNZ_CAP) b = NNZ_CAP;
      int e = b + rowCnt[i];
      if (e > NNZ_CAP) e = NNZ_CAP;
      b_r[k] = b;
      e_r[k] = e;
      float Lv = Lg[i];
      float sS = fmaxf(Sg[i], 1e-6f);
      float mnv = fmaxf(mng[i], 1e-3f);
      lvk_r[k] = 0.7369656f + 0.5f * LOG2(sS) - LOG2(mnv);
      SL_r[k] = sS * Lv;
      L_r[k] = Lv;
      lwc_r[k] = LOG2(wcg[i]);
      we_r[k] = weg[i];
      ldc_r[k] = LOG2(dcg[i]);
      de_r[k] = deg[i];
      float q0 = initQ[i];
      q1_r[k] = q0;
      q2_r[k] = q0;
      ip_r[k] = 0.f;
    }
    __syncthreads();
    for (int t = 0; t < NT; ++t) {
      for (int l = 0; l < nlv; ++l) {
#pragma unroll
        for (int k = 0; k < 4; ++k) {
          if (lev_r[k] == l) {
            int i = tid + k * 1024;
            float latv = lat[t * NR + i];
            float Qref = fmaxf(q1_r[k], 0.1f);
            float lq = LOG2(Qref);
            float lgW = fmaf(we_r[k], lq, lwc_r[k]);
            float W = EXP2(lgW);
            float aD = fmaf(de_r[k], lq, ldc_r[k]);
            float Dd = EXP2(aD);
            float lgR = fmaxf(lgW + aD - LOG2(fmaf(2.f, Dd, W)), LOG2_1E6);
            float c = fmaxf(EXP2(fmaf(0.66666667f, lgR, lvk_r[k])), 0.01f);
            float K = fmaxf(L_r[k] * RCP(c), 360.f);
            float X =
                fmaxf(0.5f - 0.5f * Qref * RCP(fmaf(W * c, SL_r[k], 1e-6f)), 0.f);
            float twoKX = 2.f * K * X;
            float C0 = fmaxf(DTSTEP - twoKX, 0.f);
            float C1 = DTSTEP + twoKX;
            float C2 = fmaxf(2.f * K - twoKX - DTSTEP, 0.f);
            float inv = RCP(C0 + C1 + C2);
            float sup = 0.f;
            for (int e = b_r[k]; e < e_r[k]; ++e) sup += Qhist[colsF[e]];
            float Icurr = sup + latv;
            float Qout =
                fmaxf((C0 * Icurr + C1 * ip_r[k] + C2 * q2_r[k]) * inv, 0.f);
            Qhist[i] = Qout;
            ip_r[k] = Icurr;
            q2_r[k] = q1_r[k];
            q1_r[k] = Qout;
            if (i == NR - 1) out[t] = Qout;
          }
        }
        __syncthreads();
      }
    }
  }
}

extern "C" void kernel_launch(void* const* d_in, const int* in_sizes, int n_in,
                              void* d_out, int out_size, void* d_ws, size_t ws_size,
                              hipStream_t stream) {
  const float* lat = (const float*)d_in[0];
  const float* iQ = (const float*)d_in[1];
  const float* Lg = (const float*)d_in[2];
  const float* Sg = (const float*)d_in[3];
  const float* mng = (const float*)d_in[4];
  const float* wcg = (const float*)d_in[5];
  const float* weg = (const float*)d_in[6];
  const float* dcg = (const float*)d_in[7];
  const float* deg = (const float*)d_in[8];
  const int* mask = (const int*)d_in[9];
  float* out = (float*)d_out;

  char* w = (char*)d_ws;
  int* rowBase = (int*)w;                        w += NR * 4;
  int* rowCnt = (int*)w;                         w += NR * 4;
  int* gctr = (int*)w;                           w += 16;
  int* meta = (int*)w;                           w += 32;  // [0]nlv [1]outlet [2]fb [4]sremCur [5]longCur
  unsigned short* colsOld = (unsigned short*)w;  w += NNZ_CAP * 2;
  unsigned short* orderG = (unsigned short*)w;   w += NR * 2;
  unsigned short* levNG = (unsigned short*)w;    w += NR * 2;
  unsigned short* scolG = (unsigned short*)w;    w += NR * 4 * 2;
  unsigned int* sremMeta = (unsigned int*)w;     w += NR * 4;
  unsigned int* longMeta = (unsigned int*)w;     w += NR * 4;
  unsigned short* sremG = (unsigned short*)w;    w += SREM_CAP * 2;
  unsigned short* longG = (unsigned short*)w;    w += LONG_CAP * 2;
  unsigned char* lsG = (unsigned char*)w;        w += NR;
  w += 16 - ((size_t)w & 15);
  float* Qhist = (float*)w;                      w += (size_t)DHIST * NR * 4;
  float* latP = (float*)w;                       w += (size_t)NT * NR * 4;
  size_t need = (size_t)(w - (char*)d_ws);
  int usePerm = (ws_size >= need) ? 1 : 0;

  hipMemsetAsync(gctr, 0, 48, stream);  // gctr + meta (incl. cursors)
  mc_build<<<NR, 64, 0, stream>>>(mask, rowBase, rowCnt, gctr, colsOld);
  mc_prep<<<1, 1024, 0, stream>>>(rowBase, rowCnt, gctr, colsOld, orderG, levNG,
                                  scolG, sremMeta, longMeta, sremG, longG, lsG,
                                  meta);
  if (usePerm)
    mc_permlat<<<(NT * NR) / 256, 256, 0, stream>>>(lat, orderG, latP);
  mc_route<<<1, 1024, 0, stream>>>(lat, latP, iQ, Lg, Sg, mng, wcg, weg, dcg,
                                   deg, rowBase, rowCnt, colsOld, orderG, levNG,
                                   scolG, sremMeta, longMeta, sremG, longG, lsG,
                                   meta, Qhist, out, usePerm);
}